// Round 2
// baseline (24.317 us; speedup 1.0000x reference)
//
#include <hip/hip_runtime.h>

// FeatureViewEncoder: per-feature Conv1d(1,H,3) + mask + max-over-time.
// Shapes: input_visit [B=128, V=200, F=64] f32, visit_mask [B,1,L=198] i32,
// conv_w [F,H=128,K=3] f32, conv_b [F,H] f32, out [B,F,H] f32.
// out[b,f,h] = max_{l valid} ( sum_k x[b,l+k,f]*w[f,h,k] + bias[f,h] ), else -1e9.

#define NEG_INF_F (-1e9f)

constexpr int B_ = 128;
constexpr int V_ = 200;
constexpr int F_ = 64;
constexpr int H_ = 128;
constexpr int K_ = 3;
constexpr int L_ = V_ - K_ + 1;  // 198

constexpr int FG = 8;         // features per block
constexpr int NTHR = 256;     // threads per block
constexpr int HPT = 4;        // h-outputs per thread (128 h / 32 threads-per-f)
constexpr int XSTR = 204;     // LDS row stride in floats (mult of 4 -> 16B-aligned quads;
                              // 204%32=12 -> row starts hit distinct banks for f=0..7)

__global__ __launch_bounds__(NTHR)
void fve_kernel(const float* __restrict__ x,     // [B,V,F]
                const int*   __restrict__ mask,  // [B,1,L]
                const float* __restrict__ w,     // [F,H,K]
                const float* __restrict__ bias,  // [F,H]
                float* __restrict__ out)         // [B,F,H]
{
    __shared__ __align__(16) float xs[FG][XSTR];

    const int b  = blockIdx.x >> 3;   // grid = B * (F/FG) = 1024
    const int fg = blockIdx.x & 7;
    const int f0 = fg * FG;
    const int t  = threadIdx.x;

    // Stage x[b, :, f0:f0+8] -> LDS transposed to xs[f_local][v].
    for (int idx = t; idx < V_ * 2; idx += NTHR) {
        const int v = idx >> 1, half = idx & 1;
        const float4 vec = *reinterpret_cast<const float4*>(
            x + ((size_t)b * V_ + v) * F_ + f0 + half * 4);
        const int fl = half * 4;
        xs[fl + 0][v] = vec.x;
        xs[fl + 1][v] = vec.y;
        xs[fl + 2][v] = vec.z;
        xs[fl + 3][v] = vec.w;
    }
    __syncthreads();

    const int f_local = t >> 5;            // 0..7
    const int f       = f0 + f_local;
    const int h0      = (t & 31) * HPT;    // 0,4,...,124

    // 12 contiguous weight floats for h0..h0+3 (layout [F,H,K]).
    const float* wp = w + ((size_t)f * H_ + h0) * K_;
    const float4 w0 = *reinterpret_cast<const float4*>(wp);
    const float4 w1 = *reinterpret_cast<const float4*>(wp + 4);
    const float4 w2 = *reinterpret_cast<const float4*>(wp + 8);
    const float4 bb = *reinterpret_cast<const float4*>(bias + (size_t)f * H_ + h0);

    float m0 = NEG_INF_F, m1 = NEG_INF_F, m2 = NEG_INF_F, m3 = NEG_INF_F;

    // Wave-uniform mask row (b and loop index uniform -> scalar loads).
    const int* __restrict__ mrow = mask + b * L_;

    // Rolling window: quad i = x[4i..4i+3]. Per group of 4 l: one ds_read_b128.
    const float4* xq = reinterpret_cast<const float4*>(&xs[f_local][0]);
    float4 A = xq[0];

#define BODY(X0, X1, X2)                                                      \
    do {                                                                      \
        const float c0 = fmaf((X0), w0.x, fmaf((X1), w0.y, fmaf((X2), w0.z, bb.x))); \
        const float c1 = fmaf((X0), w0.w, fmaf((X1), w1.x, fmaf((X2), w1.y, bb.y))); \
        const float c2 = fmaf((X0), w1.z, fmaf((X1), w1.w, fmaf((X2), w2.x, bb.z))); \
        const float c3 = fmaf((X0), w2.y, fmaf((X1), w2.z, fmaf((X2), w2.w, bb.w))); \
        m0 = fmaxf(m0, c0);                                                   \
        m1 = fmaxf(m1, c1);                                                   \
        m2 = fmaxf(m2, c2);                                                   \
        m3 = fmaxf(m3, c3);                                                   \
    } while (0)

    for (int i = 0; i < 49; ++i) {          // l = 4i+j, j=0..3, covers l=0..195
        const float4 Bq = xq[i + 1];
        const int l0 = 4 * i;
        if (mrow[l0 + 0] != 0) BODY(A.x, A.y, A.z);
        if (mrow[l0 + 1] != 0) BODY(A.y, A.z, A.w);
        if (mrow[l0 + 2] != 0) BODY(A.z, A.w, Bq.x);
        if (mrow[l0 + 3] != 0) BODY(A.w, Bq.x, Bq.y);
        A = Bq;
    }
    // Tail: l = 196, 197 use only quad 49 (now in A).
    if (mrow[196] != 0) BODY(A.x, A.y, A.z);
    if (mrow[197] != 0) BODY(A.y, A.z, A.w);
#undef BODY

    *reinterpret_cast<float4*>(out + ((size_t)b * F_ + f) * H_ + h0) =
        make_float4(m0, m1, m2, m3);
}

extern "C" void kernel_launch(void* const* d_in, const int* in_sizes, int n_in,
                              void* d_out, int out_size, void* d_ws, size_t ws_size,
                              hipStream_t stream) {
    const float* x    = (const float*)d_in[0];  // input_visit
    const int*   mask = (const int*)d_in[1];    // visit_mask
    const float* w    = (const float*)d_in[2];  // conv_w
    const float* bias = (const float*)d_in[3];  // conv_b
    float* out = (float*)d_out;

    const int grid = B_ * (F_ / FG);  // 1024
    fve_kernel<<<grid, NTHR, 0, stream>>>(x, mask, w, bias, out);
}

// Round 3
// 17.765 us; speedup vs baseline: 1.3688x; 1.3688x over previous
//
#include <hip/hip_runtime.h>

// FeatureViewEncoder: per-feature Conv1d(1,H,3) + mask + max-over-time.
// out[b,f,h] = max_{l: mask[b,l]!=0} ( sum_k x[b,l+k,f]*w[f,h,k] + bias[f,h] ), else -1e9.
// Structure: valid-l compaction (branch-free inner loop) + HPT=8 LDS amortization.

#define NEG_INF_F (-1e9f)

constexpr int B_ = 128;
constexpr int V_ = 200;
constexpr int F_ = 64;
constexpr int H_ = 128;
constexpr int L_ = V_ - 3 + 1;   // 198

constexpr int NTHR = 256;
constexpr int HPT  = 8;            // h-outputs per thread
constexpr int TPF  = H_ / HPT;     // 16 threads per feature
constexpr int FG   = NTHR / TPF;   // 16 features per block
constexpr int XSTR = 204;          // LDS row stride (mult of 4; 204%32=12 spreads row-start banks)

__global__ __launch_bounds__(NTHR)
void fve_kernel(const float* __restrict__ x,     // [B,V,F]
                const int*   __restrict__ mask,  // [B,1,L]
                const float* __restrict__ w,     // [F,H,K]
                const float* __restrict__ bias,  // [F,H]
                float* __restrict__ out)         // [B,F,H]
{
    __shared__ __align__(16) float xs[FG][XSTR];
    __shared__ __align__(16) int   vlist[((L_ + 3) / 4) * 4];  // int4-readable
    __shared__ int vcnt;

    const int b  = blockIdx.x >> 2;        // grid = B * (F/FG) = 512
    const int f0 = (blockIdx.x & 3) * FG;
    const int t  = threadIdx.x;

    if (t == 0) vcnt = 0;
    __syncthreads();

    // Stage x[b, :, f0:f0+16] -> LDS transposed to xs[f_local][v].
    for (int idx = t; idx < V_ * 4; idx += NTHR) {
        const int v = idx >> 2, q = idx & 3;
        const float4 vec = *reinterpret_cast<const float4*>(
            x + ((size_t)b * V_ + v) * F_ + f0 + q * 4);
        const int fl = q * 4;
        xs[fl + 0][v] = vec.x;
        xs[fl + 1][v] = vec.y;
        xs[fl + 2][v] = vec.z;
        xs[fl + 3][v] = vec.w;
    }

    // Compact valid time-steps (order irrelevant for max).
    for (int l = t; l < L_; l += NTHR) {
        if (mask[b * L_ + l] != 0) {
            const int p = atomicAdd(&vcnt, 1);
            vlist[p] = l;
        }
    }
    __syncthreads();

    const int f_local = t >> 4;            // 0..15
    const int f       = f0 + f_local;
    const int h0      = (t & 15) * HPT;    // 0,8,...,120

    // 24 contiguous weight floats (h0..h0+7, K=3) + 8 bias, into registers.
    const float* wp = w + ((size_t)f * H_ + h0) * 3;
    float wt[24];
#pragma unroll
    for (int j = 0; j < 6; ++j)
        *reinterpret_cast<float4*>(&wt[j * 4]) =
            *reinterpret_cast<const float4*>(wp + j * 4);

    float bb[8];
    *reinterpret_cast<float4*>(&bb[0]) =
        *reinterpret_cast<const float4*>(bias + (size_t)f * H_ + h0);
    *reinterpret_cast<float4*>(&bb[4]) =
        *reinterpret_cast<const float4*>(bias + (size_t)f * H_ + h0 + 4);

    float m[8];
#pragma unroll
    for (int hh = 0; hh < 8; ++hh) m[hh] = NEG_INF_F;

    const float* row = &xs[f_local][0];
    const int n  = vcnt;
    const int n4 = n & ~3;
    const int4* vq = reinterpret_cast<const int4*>(vlist);

#define PROC(lv)                                                              \
    do {                                                                      \
        const int   l  = (lv);                                                \
        const float x0 = row[l], x1 = row[l + 1], x2 = row[l + 2];            \
        _Pragma("unroll")                                                     \
        for (int hh = 0; hh < 8; ++hh) {                                      \
            const float c = fmaf(x0, wt[3 * hh],                              \
                            fmaf(x1, wt[3 * hh + 1],                          \
                            fmaf(x2, wt[3 * hh + 2], bb[hh])));               \
            m[hh] = fmaxf(m[hh], c);                                          \
        }                                                                     \
    } while (0)

    for (int i = 0; i < n4; i += 4) {      // 1 ds_read_b128 per 4 l's
        const int4 ls = vq[i >> 2];
        PROC(ls.x);
        PROC(ls.y);
        PROC(ls.z);
        PROC(ls.w);
    }
    for (int i = n4; i < n; ++i) PROC(vlist[i]);
#undef PROC

    float* op = out + ((size_t)b * F_ + f) * H_ + h0;
    *reinterpret_cast<float4*>(op)     = make_float4(m[0], m[1], m[2], m[3]);
    *reinterpret_cast<float4*>(op + 4) = make_float4(m[4], m[5], m[6], m[7]);
}

extern "C" void kernel_launch(void* const* d_in, const int* in_sizes, int n_in,
                              void* d_out, int out_size, void* d_ws, size_t ws_size,
                              hipStream_t stream) {
    const float* x    = (const float*)d_in[0];  // input_visit
    const int*   mask = (const int*)d_in[1];    // visit_mask
    const float* w    = (const float*)d_in[2];  // conv_w
    const float* bias = (const float*)d_in[3];  // conv_b
    float* out = (float*)d_out;

    const int grid = B_ * (F_ / FG);  // 512
    fve_kernel<<<grid, NTHR, 0, stream>>>(x, mask, w, bias, out);
}

// Round 4
// 17.184 us; speedup vs baseline: 1.4151x; 1.0338x over previous
//
#include <hip/hip_runtime.h>

// FeatureViewEncoder: per-feature Conv1d(1,H,3) + mask + max-over-time.
// out[b,f,h] = max_{l: mask[b,l]!=0} ( sum_k x[b,l+k,f]*w[f,h,k] + bias[f,h] ), else -1e9.
// Structure: valid-l compaction + HPT=8, h-pair packed math (v_pk_fma_f32/v_pk_max_f32).

#define NEG_INF_F (-1e9f)

typedef float v2f __attribute__((ext_vector_type(2)));

constexpr int B_ = 128;
constexpr int V_ = 200;
constexpr int F_ = 64;
constexpr int H_ = 128;
constexpr int L_ = V_ - 3 + 1;   // 198

constexpr int NTHR = 256;
constexpr int HPT  = 8;            // h-outputs per thread (4 packed pairs)
constexpr int TPF  = H_ / HPT;     // 16 threads per feature
constexpr int FG   = NTHR / TPF;   // 16 features per block
constexpr int XSTR = 204;          // LDS row stride (mult of 4; spreads row-start banks)

__global__ __launch_bounds__(NTHR)
void fve_kernel(const float* __restrict__ x,     // [B,V,F]
                const int*   __restrict__ mask,  // [B,1,L]
                const float* __restrict__ w,     // [F,H,K]
                const float* __restrict__ bias,  // [F,H]
                float* __restrict__ out)         // [B,F,H]
{
    __shared__ __align__(16) float xs[FG][XSTR];
    __shared__ __align__(16) int   vlist[((L_ + 3) / 4) * 4];
    __shared__ int vcnt;

    const int b  = blockIdx.x >> 2;        // grid = B * (F/FG) = 512
    const int f0 = (blockIdx.x & 3) * FG;
    const int t  = threadIdx.x;

    if (t == 0) vcnt = 0;
    __syncthreads();

    // Stage x[b, :, f0:f0+16] -> LDS transposed to xs[f_local][v].
    for (int idx = t; idx < V_ * 4; idx += NTHR) {
        const int v = idx >> 2, q = idx & 3;
        const float4 vec = *reinterpret_cast<const float4*>(
            x + ((size_t)b * V_ + v) * F_ + f0 + q * 4);
        const int fl = q * 4;
        xs[fl + 0][v] = vec.x;
        xs[fl + 1][v] = vec.y;
        xs[fl + 2][v] = vec.z;
        xs[fl + 3][v] = vec.w;
    }

    // Compact valid time-steps (order irrelevant for max).
    for (int l = t; l < L_; l += NTHR) {
        if (mask[b * L_ + l] != 0) {
            const int p = atomicAdd(&vcnt, 1);
            vlist[p] = l;
        }
    }
    __syncthreads();

    const int f_local = t >> 4;            // 0..15
    const int f       = f0 + f_local;
    const int h0      = (t & 15) * HPT;    // 0,8,...,120

    // Load 24 weight floats + 8 bias, repack into h-pairs:
    // wp0[p] = (w[h0+2p, k=0], w[h0+2p+1, k=0]) etc.  Layout in mem: [h][k] contiguous.
    const float* wpތ = w + ((size_t)f * H_ + h0) * 3;
    float wt[24];
#pragma unroll
    for (int j = 0; j < 6; ++j)
        *reinterpret_cast<float4*>(&wt[j * 4]) =
            *reinterpret_cast<const float4*>(wpތ + j * 4);

    float bsc[8];
    *reinterpret_cast<float4*>(&bsc[0]) =
        *reinterpret_cast<const float4*>(bias + (size_t)f * H_ + h0);
    *reinterpret_cast<float4*>(&bsc[4]) =
        *reinterpret_cast<const float4*>(bias + (size_t)f * H_ + h0 + 4);

    v2f wp0[4], wp1[4], wp2[4], bpk[4], mpk[4];
#pragma unroll
    for (int p = 0; p < 4; ++p) {
        wp0[p] = (v2f){wt[6 * p + 0], wt[6 * p + 3]};
        wp1[p] = (v2f){wt[6 * p + 1], wt[6 * p + 4]};
        wp2[p] = (v2f){wt[6 * p + 2], wt[6 * p + 5]};
        bpk[p] = (v2f){bsc[2 * p], bsc[2 * p + 1]};
        mpk[p] = (v2f){NEG_INF_F, NEG_INF_F};
    }

    const float* row = &xs[f_local][0];
    const int n  = vcnt;
    const int n4 = n & ~3;
    const int4* vq = reinterpret_cast<const int4*>(vlist);

#define PROC(lv)                                                              \
    do {                                                                      \
        const int   l  = (lv);                                                \
        const float x0 = row[l], x1 = row[l + 1], x2 = row[l + 2];            \
        const v2f X0 = (v2f){x0, x0};                                         \
        const v2f X1 = (v2f){x1, x1};                                         \
        const v2f X2 = (v2f){x2, x2};                                         \
        _Pragma("unroll")                                                     \
        for (int p = 0; p < 4; ++p) {                                         \
            const v2f c = __builtin_elementwise_fma(X0, wp0[p],               \
                          __builtin_elementwise_fma(X1, wp1[p],               \
                          __builtin_elementwise_fma(X2, wp2[p], bpk[p])));    \
            mpk[p] = __builtin_elementwise_max(mpk[p], c);                    \
        }                                                                     \
    } while (0)

    for (int i = 0; i < n4; i += 4) {      // 1 ds_read_b128 of vlist per 4 l's
        const int4 ls = vq[i >> 2];
        PROC(ls.x);
        PROC(ls.y);
        PROC(ls.z);
        PROC(ls.w);
    }
    for (int i = n4; i < n; ++i) PROC(vlist[i]);
#undef PROC

    float* op = out + ((size_t)b * F_ + f) * H_ + h0;
    *reinterpret_cast<float4*>(op) =
        make_float4(mpk[0].x, mpk[0].y, mpk[1].x, mpk[1].y);
    *reinterpret_cast<float4*>(op + 4) =
        make_float4(mpk[2].x, mpk[2].y, mpk[3].x, mpk[3].y);
}

extern "C" void kernel_launch(void* const* d_in, const int* in_sizes, int n_in,
                              void* d_out, int out_size, void* d_ws, size_t ws_size,
                              hipStream_t stream) {
    const float* x    = (const float*)d_in[0];  // input_visit
    const int*   mask = (const int*)d_in[1];    // visit_mask
    const float* w    = (const float*)d_in[2];  // conv_w
    const float* bias = (const float*)d_in[3];  // conv_b
    float* out = (float*)d_out;

    const int grid = B_ * (F_ / FG);  // 512
    fve_kernel<<<grid, NTHR, 0, stream>>>(x, mask, w, bias, out);
}